// Round 6
// baseline (1660.043 us; speedup 1.0000x reference)
//
#include <hip/hip_runtime.h>
#include <hip/hip_bf16.h>

#define Bn 32
#define Sn 400
#define Tn 100
#define Vn 32000
#define OOVn 100
#define VEn 32100
#define En 512
#define Un 256
#define AUn 256
#define GPn 256
#define ENCn 512
#define Z4n 1024

typedef __attribute__((ext_vector_type(8))) short bf16x8;
typedef __attribute__((ext_vector_type(4))) float f32x4;
typedef unsigned short ushort_t;
typedef unsigned long long u64;

__device__ __forceinline__ float rcp_f(float x){ return __builtin_amdgcn_rcpf(x); }
__device__ __forceinline__ float tanh_fast(float x){
  float e2 = __expf(2.f*x);
  return 1.f - 2.f*rcp_f(e2 + 1.f);
}
__device__ __forceinline__ float sigmoid_f(float x){ return 1.f/(1.f+__expf(-x)); }
__device__ __forceinline__ ushort_t f2bf(float f){
  unsigned u = __float_as_uint(f);
  unsigned r = (u + 0x7FFFu + ((u>>16)&1u)) >> 16;   // RNE
  return (ushort_t)r;
}
__device__ __forceinline__ u64 shfl_xor_u64(u64 v, int m){
  unsigned lo = (unsigned)v, hi = (unsigned)(v>>32);
  lo = (unsigned)__shfl_xor((int)lo, m);
  hi = (unsigned)__shfl_xor((int)hi, m);
  return ((u64)hi<<32)|(u64)lo;
}

// relaxed agent-scope ops: coherence-point loads/stores, no cache maintenance
__device__ __forceinline__ void st_rlx(float* p, float v){
  __hip_atomic_store(p, v, __ATOMIC_RELAXED, __HIP_MEMORY_SCOPE_AGENT);
}
__device__ __forceinline__ float ld_rlx(const float* p){
  return __hip_atomic_load(p, __ATOMIC_RELAXED, __HIP_MEMORY_SCOPE_AGENT);
}
__device__ __forceinline__ void st_flag(unsigned* p, unsigned v){
  __hip_atomic_store(p, v, __ATOMIC_RELAXED, __HIP_MEMORY_SCOPE_AGENT);
}
__device__ __forceinline__ unsigned ld_flag(const unsigned* p){
  return __hip_atomic_load(p, __ATOMIC_RELAXED, __HIP_MEMORY_SCOPE_AGENT);
}

// ---------------- pre-loop kernels ----------------

__global__ __launch_bounds__(256) void k_gather(const int* __restrict__ gt,
    const float* __restrict__ emb, float* __restrict__ Xall){
  int r = blockIdx.x;                 // r = t*32 + b
  int t = r >> 5, b = r & 31;
  int tok = gt[b*Tn + t];
  const float* src = emb + (size_t)tok*En;
  float* dst = Xall + (size_t)r*En;
  for (int i = threadIdx.x; i < En; i += 256) dst[i] = src[i];
}

// Zx = Xall @ Wk + bias   [3200,512]@[512,1024], f32 tiled 64x64
__global__ __launch_bounds__(256) void k_zx(const float* __restrict__ X,
    const float* __restrict__ Wk, const float* __restrict__ bias, float* __restrict__ Zx){
  __shared__ float As[64][17];
  __shared__ float Bs[16][65];
  int r0 = blockIdx.x * 64;
  int c0 = blockIdx.y * 64;
  int tid = threadIdx.x;
  int ty = tid >> 4, tx = tid & 15;
  float acc[4][4] = {};
  for (int k0 = 0; k0 < En; k0 += 16){
    #pragma unroll
    for (int p = 0; p < 4; ++p){
      int row = (tid>>4) + p*16, kk = tid & 15;
      As[row][kk] = X[(size_t)(r0+row)*En + k0 + kk];
    }
    #pragma unroll
    for (int p = 0; p < 4; ++p){
      int kk = (tid>>6) + p*4, cc = tid & 63;
      Bs[kk][cc] = Wk[(size_t)(k0+kk)*Z4n + c0 + cc];
    }
    __syncthreads();
    #pragma unroll
    for (int kk = 0; kk < 16; ++kk){
      float av[4], bv[4];
      #pragma unroll
      for (int i=0;i<4;++i) av[i] = As[ty*4+i][kk];
      #pragma unroll
      for (int j=0;j<4;++j) bv[j] = Bs[kk][tx*4+j];
      #pragma unroll
      for (int i=0;i<4;++i)
        #pragma unroll
        for (int j=0;j<4;++j) acc[i][j] += av[i]*bv[j];
    }
    __syncthreads();
  }
  #pragma unroll
  for (int i=0;i<4;++i){
    int row = r0 + ty*4 + i;
    #pragma unroll
    for (int j=0;j<4;++j){
      int col = c0 + tx*4 + j;
      Zx[(size_t)row*Z4n + col] = acc[i][j] + bias[col];
    }
  }
}

// gpx[t,:] = x[t,b=0,:] @ gp_Wi + gp_bi
__global__ __launch_bounds__(256) void k_gpx(const float* __restrict__ Xall,
    const float* __restrict__ Wi, const float* __restrict__ bi, float* __restrict__ gpx){
  int t = blockIdx.x, j = threadIdx.x;
  const float* x = Xall + (size_t)(t*Bn + 0)*En;
  float acc = bi[j];
  for (int u = 0; u < En; ++u) acc += x[u]*Wi[u*GPn + j];
  gpx[t*GPn + j] = acc;
}

// W2 [256][32000] f32 -> W2T [32000][256] bf16 (LDS-tiled transpose)
__global__ __launch_bounds__(256) void k_w2t(const float* __restrict__ W2,
    ushort_t* __restrict__ W2T){
  __shared__ float tile[64][65];
  int n0 = blockIdx.x * 64;   // 500
  int k0 = blockIdx.y * 64;   // 4
  int tx = threadIdx.x & 63, ty4 = threadIdx.x >> 6;
  #pragma unroll
  for (int i = 0; i < 16; ++i){
    int k = ty4 + i*4;
    tile[k][tx] = W2[(size_t)(k0+k)*Vn + n0 + tx];
  }
  __syncthreads();
  #pragma unroll
  for (int i = 0; i < 16; ++i){
    int n = ty4 + i*4;
    W2T[(size_t)(n0+n)*Un + k0 + tx] = f2bf(tile[tx][n]);
  }
}

// ---------------- persistent 256-block recurrent kernel ----------------
// b = blockIdx&31, k = blockIdx>>5. ONE flag barrier per step.
// waves 0-7 (C): D(t-1) + dec-sum + scores(t) + psum(t)
// waves 8-15 (A): LSTM(t+1) + h publish + dec partials(t+1)
// decp/psum double-buffered; sc_lds LDS double-buffered; cov rows wave-owned.

__global__ __launch_bounds__(1024, 1) void k_loop(
    const float* __restrict__ Zx, const float* __restrict__ Wr,
    const float* __restrict__ Wd, const float* __restrict__ bd,
    const float* __restrict__ Wc, const float* __restrict__ Wa,
    const float* __restrict__ enc_attn,
    const float* __restrict__ h0, const float* __restrict__ c0,
    float* __restrict__ h_all, float* __restrict__ decp,
    float* __restrict__ c0_all, float* __restrict__ a_all,
    float* __restrict__ covloss, float* __restrict__ psum,
    unsigned* __restrict__ bars){
  __shared__ float Wr_lds[256*128];     // 128 KB: Wr cols {32k+i+256q}
  __shared__ float hprev[Un];
  __shared__ float ppart[4][132];
  __shared__ float hnew[32], cown[32];
  __shared__ float dec_lds[AUn];
  __shared__ float cov_lds[64];
  __shared__ float sc_lds[2][64];
  __shared__ float wred[8];

  const int b = blockIdx.x & 31, k = blockIdx.x >> 5;
  const int tid = threadIdx.x, lane = tid & 63, w = tid >> 6;
  unsigned* flags = bars + b*8*32;          // 8 slots, 128 B apart
  unsigned* myflag = flags + k*32;

  for (int idx = tid; idx < 256*128; idx += 1024){
    int u = idx >> 7, jl = idx & 127;
    int gcol = 32*k + (jl & 31) + 256*(jl >> 5);
    Wr_lds[idx] = Wr[(size_t)u*Z4n + gcol];
  }
  if (tid < 32) cown[tid] = c0[b*Un + 32*k + tid];
  if (tid < 50) cov_lds[tid] = 0.f;
  const float4 wc4 = *(const float4*)(Wc + lane*4);
  const float4 wa4 = *(const float4*)(Wa + lane*4);
  __syncthreads();

  // ======== pre-step: compute h(0), decp[0], signal flag=1 ========
  {
    if (tid >= 512 && tid < 768) hprev[tid-512] = h0[b*Un + (tid-512)];
    __syncthreads();
    if (w >= 8){
      int a = tid - 512;
      int p = a >> 7, jl = a & 127;
      float acc = 0.f;
      const float* wr = Wr_lds + (p*64)*128 + jl;
      const float* hb = hprev + p*64;
      #pragma unroll 8
      for (int uu = 0; uu < 64; ++uu) acc += hb[uu]*wr[uu*128];
      ppart[p][jl] = acc;
    }
    __syncthreads();
    if (w == 8){
      int jlo = lane, jhi = lane + 64;
      int glo = 32*k + (jlo & 31) + 256*(jlo >> 5);
      int ghi = 32*k + (jhi & 31) + 256*(jhi >> 5);
      const float* zr = Zx + (size_t)(0*Bn + b)*Z4n;
      float zl = ppart[0][jlo]+ppart[1][jlo]+ppart[2][jlo]+ppart[3][jlo] + zr[glo];
      float zh = ppart[0][jhi]+ppart[1][jhi]+ppart[2][jhi]+ppart[3][jhi] + zr[ghi];
      float zf = __shfl(zl, (lane+32)&63);
      float zo = __shfl(zh, (lane+32)&63);
      if (lane < 32){
        float cn = sigmoid_f(zf)*cown[lane] + sigmoid_f(zl)*tanhf(zh);
        float hn = sigmoid_f(zo)*tanhf(cn);
        cown[lane] = cn; hnew[lane] = hn;
        int col = 32*k + lane;
        st_rlx(h_all + (size_t)(0*Bn + b)*Un + col, hn);
        if (b == 0) c0_all[0*Un + col] = cn;
      }
    }
    __syncthreads();
    if (w >= 8 && (tid - 512) < 256){
      int c = tid - 512;
      float acc = 0.f;
      const float* wdh = Wd + (size_t)(32*k)*AUn + c;
      #pragma unroll 8
      for (int u = 0; u < 32; ++u) acc += hnew[u]*wdh[(size_t)u*AUn];
      const float* wdc = Wd + (size_t)(Un + 32*k)*AUn + c;
      #pragma unroll 8
      for (int u = 0; u < 32; ++u) acc += cown[u]*wdc[(size_t)u*AUn];
      st_rlx(decp + 0*(Bn*8*256) + (size_t)(b*8 + k)*256 + c, acc);
    }
    __syncthreads();
    if (tid == 0) st_flag(myflag, 1u);
  }

  // ======== main loop ========
  for (int t = 0; t < Tn; ++t){
    const int cur = t & 1, nxt = (t+1) & 1, prv = cur ^ 1;
    // per-wave wait: flags >= t+1  (h(t), decp[cur], psum[prv](t-1) visible)
    if (lane < 8){
      while (ld_flag(flags + lane*32) < (unsigned)(t+1))
        __builtin_amdgcn_s_sleep(1);
    }
    // ---- S0 ----
    if (w < 8){
      if (t > 0){
        float pv = (lane < 8) ? ld_rlx(psum + prv*(Bn*8) + b*8 + lane) : 0.f;
        pv += __shfl_xor(pv, 1); pv += __shfl_xor(pv, 2); pv += __shfl_xor(pv, 4);
        float inv = 1.f / __shfl(pv, 0);
        float clp = 0.f;
        if (lane < 7){
          int row = w + 8*lane;
          if (row < 50){
            float aa = sc_lds[prv][row] * inv;
            float co = cov_lds[row];
            a_all[(size_t)((t-1)*Bn + b)*Sn + 50*k + row] = aa;
            cov_lds[row] = co + aa;
            clp = fminf(co, aa);
          }
        }
        clp += __shfl_xor(clp, 1); clp += __shfl_xor(clp, 2); clp += __shfl_xor(clp, 4);
        if (lane == 0) atomicAdd(&covloss[b*Tn + (t-1)], clp);
      }
      if (tid < 256){
        float s = bd[tid];
        const float* dp = decp + cur*(Bn*8*256) + (size_t)(b*8)*256 + tid;
        #pragma unroll
        for (int q = 0; q < 8; ++q) s += ld_rlx(dp + q*256);
        dec_lds[tid] = s;
      }
    } else if (t + 1 < Tn){
      int a = tid - 512;
      if (a < 256) hprev[a] = ld_rlx(h_all + (size_t)(t*Bn + b)*Un + a);
    }
    __syncthreads();
    // ---- S1: C scores(t) ; A ppart(t+1) ----
    if (w < 8){
      const float4 da = *(const float4*)(dec_lds + lane*4);
      float wsum = 0.f;
      for (int sl = w; sl < 50; sl += 8){
        float cvv = cov_lds[sl];
        const float4 e = *(const float4*)(enc_attn + ((size_t)(b*Sn + 50*k + sl))*AUn + lane*4);
        float psc = tanh_fast(e.x + cvv*wc4.x + da.x)*wa4.x
                  + tanh_fast(e.y + cvv*wc4.y + da.y)*wa4.y
                  + tanh_fast(e.z + cvv*wc4.z + da.z)*wa4.z
                  + tanh_fast(e.w + cvv*wc4.w + da.w)*wa4.w;
        #pragma unroll
        for (int m = 1; m < 64; m <<= 1) psc += __shfl_xor(psc, m);
        if (lane == 0){
          float ev = __expf(psc);
          sc_lds[cur][sl] = ev;
          wsum += ev;
        }
      }
      if (lane == 0) wred[w] = wsum;
    } else if (t + 1 < Tn){
      int a = tid - 512;
      int p = a >> 7, jl = a & 127;
      float acc = 0.f;
      const float* wr = Wr_lds + (p*64)*128 + jl;
      const float* hb = hprev + p*64;
      #pragma unroll 8
      for (int uu = 0; uu < 64; ++uu) acc += hb[uu]*wr[uu*128];
      ppart[p][jl] = acc;
    }
    __syncthreads();
    // ---- S2: psum store (wave 0) ; z+gates (wave 8) ----
    if (w == 0){
      float pv = (lane < 8) ? wred[lane] : 0.f;
      pv += __shfl_xor(pv, 1); pv += __shfl_xor(pv, 2); pv += __shfl_xor(pv, 4);
      if (lane == 0) st_rlx(psum + cur*(Bn*8) + b*8 + k, pv);
    } else if (w == 8 && t + 1 < Tn){
      int jlo = lane, jhi = lane + 64;
      int glo = 32*k + (jlo & 31) + 256*(jlo >> 5);
      int ghi = 32*k + (jhi & 31) + 256*(jhi >> 5);
      const float* zr = Zx + (size_t)((t+1)*Bn + b)*Z4n;
      float zl = ppart[0][jlo]+ppart[1][jlo]+ppart[2][jlo]+ppart[3][jlo] + zr[glo];
      float zh = ppart[0][jhi]+ppart[1][jhi]+ppart[2][jhi]+ppart[3][jhi] + zr[ghi];
      float zf = __shfl(zl, (lane+32)&63);
      float zo = __shfl(zh, (lane+32)&63);
      if (lane < 32){
        float cn = sigmoid_f(zf)*cown[lane] + sigmoid_f(zl)*tanhf(zh);
        float hn = sigmoid_f(zo)*tanhf(cn);
        cown[lane] = cn; hnew[lane] = hn;
        int col = 32*k + lane;
        st_rlx(h_all + (size_t)((t+1)*Bn + b)*Un + col, hn);
        if (b == 0) c0_all[(t+1)*Un + col] = cn;
      }
    }
    __syncthreads();
    // ---- S3: dec-direct(t+1) on A ----
    if (w >= 8 && (tid - 512) < 256 && t + 1 < Tn){
      int c = tid - 512;
      float acc = 0.f;
      const float* wdh = Wd + (size_t)(32*k)*AUn + c;
      #pragma unroll 8
      for (int u = 0; u < 32; ++u) acc += hnew[u]*wdh[(size_t)u*AUn];
      const float* wdc = Wd + (size_t)(Un + 32*k)*AUn + c;
      #pragma unroll 8
      for (int u = 0; u < 32; ++u) acc += cown[u]*wdc[(size_t)u*AUn];
      st_rlx(decp + nxt*(Bn*8*256) + (size_t)(b*8 + k)*256 + c, acc);
    }
    __syncthreads();   // drains vmcnt before flag
    if (tid == 0) st_flag(myflag, (unsigned)(t + 2));
  }

  // ======== post-loop: D(99) ========
  {
    if (lane < 8){
      while (ld_flag(flags + lane*32) < (unsigned)(Tn + 1))
        __builtin_amdgcn_s_sleep(1);
    }
    if (w < 8){
      const int prv = (Tn - 1) & 1;
      float pv = (lane < 8) ? ld_rlx(psum + prv*(Bn*8) + b*8 + lane) : 0.f;
      pv += __shfl_xor(pv, 1); pv += __shfl_xor(pv, 2); pv += __shfl_xor(pv, 4);
      float inv = 1.f / __shfl(pv, 0);
      float clp = 0.f;
      if (lane < 7){
        int row = w + 8*lane;
        if (row < 50){
          float aa = sc_lds[prv][row] * inv;
          float co = cov_lds[row];
          a_all[(size_t)((Tn-1)*Bn + b)*Sn + 50*k + row] = aa;
          clp = fminf(co, aa);
        }
      }
      clp += __shfl_xor(clp, 1); clp += __shfl_xor(clp, 2); clp += __shfl_xor(clp, 4);
      if (lane == 0) atomicAdd(&covloss[b*Tn + (Tn-1)], clp);
    }
  }
}

// ---------------- post-loop kernels ----------------

// hid = h_all @ W1 + b1 -> bf16    (block per t)
__global__ __launch_bounds__(256) void k_hid(const float* __restrict__ h_all,
    const float* __restrict__ W1, const float* __restrict__ b1, ushort_t* __restrict__ hid){
  __shared__ float hl[Bn*Un];
  int t = blockIdx.x, tid = threadIdx.x;
  for (int i = tid; i < Bn*Un; i += 256) hl[i] = h_all[(size_t)t*Bn*Un + i];
  __syncthreads();
  int j = tid;
  float bj = b1[j];
  float acc[32];
  #pragma unroll
  for (int r = 0; r < 32; ++r) acc[r] = bj;
  for (int u = 0; u < Un; ++u){
    float wv = W1[u*Un + j];
    #pragma unroll
    for (int r = 0; r < 32; ++r) acc[r] += hl[r*Un + u]*wv;
  }
  #pragma unroll
  for (int r = 0; r < 32; ++r) hid[(size_t)(t*Bn + r)*Un + j] = f2bf(acc[r]);
}

// pg[t] via row-0 quirk
__global__ __launch_bounds__(256) void k_pg(const float* __restrict__ a_all,
    const float* __restrict__ enc_out, const float* __restrict__ h_all,
    const float* __restrict__ c0_all, const float* __restrict__ gpWs,
    const float* __restrict__ gpWc, const float* __restrict__ gpx,
    const float* __restrict__ gpWg, float* __restrict__ pg){
  __shared__ float al[Sn];
  __shared__ float cv[ENCn];
  __shared__ float red[4];
  int t = blockIdx.x, tid = threadIdx.x;
  for (int s = tid; s < Sn; s += 256) al[s] = a_all[(size_t)(t*Bn + 0)*Sn + s];
  __syncthreads();
  for (int e = tid; e < ENCn; e += 256){
    float acc = 0.f;
    for (int s = 0; s < Sn; ++s) acc += enc_out[(size_t)s*ENCn + e]*al[s];
    cv[e] = acc;
  }
  __syncthreads();
  int j = tid;
  float g = gpx[t*GPn + j];
  const float* h0r = h_all + (size_t)t*Bn*Un;       // b = 0 row
  const float* c0r = c0_all + t*Un;
  for (int u = 0; u < Un; ++u) g += h0r[u]*gpWs[u*GPn + j];
  for (int u = 0; u < Un; ++u) g += c0r[u]*gpWs[(Un+u)*GPn + j];
  for (int e = 0; e < ENCn; ++e) g += cv[e]*gpWc[e*GPn + j];
  float v = g * gpWg[j];
  int lane = tid & 63, wv2 = tid >> 6;
  #pragma unroll
  for (int m = 1; m < 64; m <<= 1) v += __shfl_xor(v, m);
  if (lane == 0) red[wv2] = v;
  __syncthreads();
  if (tid == 0) pg[t] = 1.f/(1.f+__expf(-(red[0]+red[1]+red[2]+red[3])));
}

// single-pass GEMM: probs <- exp(logit + b2) (unnormalized), Ssum += row sums
__global__ __launch_bounds__(256) void k_gemm(const ushort_t* __restrict__ A,
    const ushort_t* __restrict__ Bw, const float* __restrict__ b2,
    float* __restrict__ Ssum, float* __restrict__ probs){
  int r0 = blockIdx.x * 64;
  int n0 = blockIdx.y * 256;
  int tid = threadIdx.x;
  __shared__ ushort_t Bs[64*264];          // [64 n][256 k + pad8]
  int lane = tid & 63, w = tid >> 6;
  bf16x8 af[8];
  {
    const ushort_t* ar = A + (size_t)(r0 + w*16 + (lane&15))*Un + (lane>>4)*8;
    #pragma unroll
    for (int kk = 0; kk < 8; ++kk) af[kk] = *(const bf16x8*)(ar + kk*32);
  }
  f32x4 acc[16];
  #pragma unroll
  for (int i = 0; i < 16; ++i) acc[i] = (f32x4){0.f,0.f,0.f,0.f};

  for (int nsub = 0; nsub < 4; ++nsub){
    __syncthreads();
    {
      const ushort_t* gb = Bw + (size_t)(n0 + nsub*64)*Un;
      #pragma unroll
      for (int i = 0; i < 8; ++i){
        int chunk = tid + i*256;
        int rr = chunk >> 5, cc = chunk & 31;
        uint4 d = *(const uint4*)(gb + rr*Un + cc*8);
        *(uint4*)(Bs + rr*264 + cc*8) = d;
      }
    }
    __syncthreads();
    #pragma unroll
    for (int kk = 0; kk < 8; ++kk){
      #pragma unroll
      for (int ntl = 0; ntl < 4; ++ntl){
        bf16x8 bf = *(const bf16x8*)(Bs + (ntl*16 + (lane&15))*264 + kk*32 + (lane>>4)*8);
        acc[nsub*4+ntl] = __builtin_amdgcn_mfma_f32_16x16x32_bf16(af[kk], bf, acc[nsub*4+ntl], 0, 0, 0);
      }
    }
  }

  int rowloc = w*16 + (lane>>4)*4;
  size_t obase[4];
  #pragma unroll
  for (int i = 0; i < 4; ++i){
    int r = r0 + rowloc + i; int tt = r>>5, bb = r&31;
    obase[i] = (size_t)(bb*Tn + tt)*VEn;
  }
  float rs[4] = {0.f,0.f,0.f,0.f};
  #pragma unroll
  for (int nt = 0; nt < 16; ++nt){
    int v = n0 + (nt>>2)*64 + (nt&3)*16 + (lane&15);
    float bb = b2[v];
    #pragma unroll
    for (int i = 0; i < 4; ++i){
      float ev = __expf(acc[nt][i] + bb);
      probs[obase[i] + v] = ev;
      rs[i] += ev;
    }
  }
  #pragma unroll
  for (int m = 1; m < 16; m <<= 1)
    #pragma unroll
    for (int i = 0; i < 4; ++i) rs[i] += __shfl_xor(rs[i], m);
  if ((lane&15) == 0)
    #pragma unroll
    for (int i = 0; i < 4; ++i) atomicAdd(&Ssum[r0+rowloc+i], rs[i]);
}

// fused: scale by pg/Ssum + OOV zeros + dedup scatter + argmax -> seqs
__global__ __launch_bounds__(256) void k_post(const int* __restrict__ ext,
    const float* __restrict__ a_all, const float* __restrict__ pg,
    const float* __restrict__ Ssum, float* __restrict__ probs,
    float* __restrict__ seqs){
  __shared__ int tok[Sn];
  __shared__ float val[Sn];
  __shared__ u64 wmax[4];
  int r = blockIdx.x; int t = r>>5, b = r&31;
  float pgv = pg[t];
  float sc = pgv / Ssum[r];
  float c1 = 1.f - pgv;
  int tid = threadIdx.x;
  for (int s = tid; s < Sn; s += 256){
    tok[s] = ext[b*Sn + s];
    val[s] = c1 * a_all[(size_t)r*Sn + s];
  }
  size_t obase = (size_t)(b*Tn + t)*VEn;
  u64 pm = 0;
  for (int v = tid; v < Vn; v += 256){
    float nv = probs[obase + v] * sc;
    probs[obase + v] = nv;
    u64 p = ((u64)__float_as_uint(nv)<<32) | (u64)(0xFFFFFFFFu - (unsigned)v);
    pm = p > pm ? p : pm;
  }
  if (tid < OOVn) probs[obase + Vn + tid] = 0.f;
  __syncthreads();
  for (int s = tid; s < Sn; s += 256){
    int tk = tok[s];
    bool leader = true;
    float tot = 0.f;
    for (int s2 = 0; s2 < Sn; ++s2){
      if (tok[s2] == tk){
        if (s2 < s){ leader = false; break; }
        tot += val[s2];
      }
    }
    if (leader){
      float nv = probs[obase + tk] + tot;
      probs[obase + tk] = nv;
      u64 p = ((u64)__float_as_uint(nv)<<32) | (u64)(0xFFFFFFFFu - (unsigned)tk);
      pm = p > pm ? p : pm;
    }
  }
  #pragma unroll
  for (int m = 1; m < 64; m <<= 1){
    u64 o = shfl_xor_u64(pm, m);
    pm = o > pm ? o : pm;
  }
  int lane = tid & 63, w = tid >> 6;
  if (lane == 0) wmax[w] = pm;
  __syncthreads();
  if (tid == 0){
    u64 mm = wmax[0];
    #pragma unroll
    for (int q = 1; q < 4; ++q) mm = wmax[q] > mm ? wmax[q] : mm;
    unsigned tk = 0xFFFFFFFFu - (unsigned)(mm & 0xFFFFFFFFull);
    seqs[b*Tn + t] = (float)tk;
  }
}

// ---------------- host launch ----------------

extern "C" void kernel_launch(void* const* d_in, const int* in_sizes, int n_in,
                              void* d_out, int out_size, void* d_ws, size_t ws_size,
                              hipStream_t stream){
  (void)in_sizes; (void)n_in; (void)out_size; (void)ws_size;
  const int*   gt       = (const int*)d_in[0];
  const int*   ext      = (const int*)d_in[1];
  const float* enc_out  = (const float*)d_in[2];
  const float* enc_attn = (const float*)d_in[3];
  const float* h0       = (const float*)d_in[4];
  const float* c0       = (const float*)d_in[5];
  const float* emb      = (const float*)d_in[6];
  const float* Wk       = (const float*)d_in[7];
  const float* Wr       = (const float*)d_in[8];
  const float* lb       = (const float*)d_in[9];
  const float* Wd       = (const float*)d_in[10];
  const float* bd       = (const float*)d_in[11];
  const float* Wc       = (const float*)d_in[12];
  const float* Wa       = (const float*)d_in[13];
  const float* W1       = (const float*)d_in[14];
  const float* b1       = (const float*)d_in[15];
  const float* W2       = (const float*)d_in[16];
  const float* b2       = (const float*)d_in[17];
  const float* gpWs     = (const float*)d_in[18];
  const float* gpWc     = (const float*)d_in[19];
  const float* gpWi     = (const float*)d_in[20];
  const float* gpbi     = (const float*)d_in[21];
  const float* gpWg     = (const float*)d_in[22];

  float* probs   = (float*)d_out;
  float* seqs    = probs + (size_t)Bn*Tn*VEn;
  float* covloss = seqs + Bn*Tn;

  char* wp = (char*)d_ws;
  auto carve = [&](size_t bytes)->void*{
    void* p = (void*)wp; wp += (bytes + 255) & ~(size_t)255; return p;
  };
  float*    Xall    = (float*)carve((size_t)3200*En*4);
  float*    Zx      = (float*)carve((size_t)3200*Z4n*4);
  float*    gpx     = (float*)carve((size_t)Tn*GPn*4);
  float*    h_all   = (float*)carve((size_t)Tn*Bn*Un*4);
  float*    decp    = (float*)carve((size_t)2*Bn*8*256*4);
  float*    c0_all  = (float*)carve((size_t)Tn*Un*4);
  float*    a_all   = (float*)carve((size_t)3200*Sn*4);
  ushort_t* hid_bf  = (ushort_t*)carve((size_t)3200*Un*2);
  ushort_t* W2T     = (ushort_t*)carve((size_t)Vn*Un*2);
  float*    Ssum    = (float*)carve((size_t)3200*4);
  float*    pg      = (float*)carve((size_t)Tn*4);
  float*    psum    = (float*)carve((size_t)2*Bn*8*4);
  unsigned* bars    = (unsigned*)carve((size_t)Bn*8*32*4);

  hipMemsetAsync(Ssum, 0, 3200*4, stream);
  hipMemsetAsync(bars, 0, Bn*8*32*4, stream);
  hipMemsetAsync(covloss, 0, Bn*Tn*4, stream);

  k_gather<<<3200, 256, 0, stream>>>(gt, emb, Xall);
  k_zx    <<<dim3(50,16), 256, 0, stream>>>(Xall, Wk, lb, Zx);

  k_loop  <<<256, 1024, 0, stream>>>(Zx, Wr, Wd, bd, Wc, Wa, enc_attn,
                                     h0, c0, h_all, decp, c0_all,
                                     a_all, covloss, psum, bars);

  k_w2t <<<dim3(500,4), 256, 0, stream>>>(W2, W2T);
  k_gpx <<<Tn, 256, 0, stream>>>(Xall, gpWi, gpbi, gpx);
  k_hid <<<Tn, 256, 0, stream>>>(h_all, W1, b1, hid_bf);
  k_pg  <<<Tn, 256, 0, stream>>>(a_all, enc_out, h_all, c0_all, gpWs, gpWc, gpx, gpWg, pg);
  k_gemm<<<dim3(50,125), 256, 0, stream>>>(hid_bf, W2T, b2, Ssum, probs);
  k_post<<<3200, 256, 0, stream>>>(ext, a_all, pg, Ssum, probs, seqs);
}

// Round 7
// 1355.191 us; speedup vs baseline: 1.2250x; 1.2250x over previous
//
#include <hip/hip_runtime.h>
#include <hip/hip_bf16.h>

#define Bn 32
#define Sn 400
#define Tn 100
#define Vn 32000
#define OOVn 100
#define VEn 32100
#define En 512
#define Un 256
#define AUn 256
#define GPn 256
#define ENCn 512
#define Z4n 1024

typedef __attribute__((ext_vector_type(8))) short bf16x8;
typedef __attribute__((ext_vector_type(4))) float f32x4;
typedef unsigned short ushort_t;
typedef unsigned long long u64;

__device__ __forceinline__ float rcp_f(float x){ return __builtin_amdgcn_rcpf(x); }
__device__ __forceinline__ float tanh_fast(float x){
  float e2 = __expf(2.f*x);
  return 1.f - 2.f*rcp_f(e2 + 1.f);
}
__device__ __forceinline__ float sigmoid_f(float x){ return 1.f/(1.f+__expf(-x)); }
__device__ __forceinline__ ushort_t f2bf(float f){
  unsigned u = __float_as_uint(f);
  unsigned r = (u + 0x7FFFu + ((u>>16)&1u)) >> 16;   // RNE
  return (ushort_t)r;
}
__device__ __forceinline__ u64 shfl_xor_u64(u64 v, int m){
  unsigned lo = (unsigned)v, hi = (unsigned)(v>>32);
  lo = (unsigned)__shfl_xor((int)lo, m);
  hi = (unsigned)__shfl_xor((int)hi, m);
  return ((u64)hi<<32)|(u64)lo;
}

// relaxed agent-scope ops: coherence-point loads/stores, no cache maintenance
__device__ __forceinline__ void st_rlx(float* p, float v){
  __hip_atomic_store(p, v, __ATOMIC_RELAXED, __HIP_MEMORY_SCOPE_AGENT);
}
__device__ __forceinline__ float ld_rlx(const float* p){
  return __hip_atomic_load(p, __ATOMIC_RELAXED, __HIP_MEMORY_SCOPE_AGENT);
}
__device__ __forceinline__ void st_flag(unsigned* p, unsigned v){
  __hip_atomic_store(p, v, __ATOMIC_RELAXED, __HIP_MEMORY_SCOPE_AGENT);
}
__device__ __forceinline__ unsigned ld_flag(const unsigned* p){
  return __hip_atomic_load(p, __ATOMIC_RELAXED, __HIP_MEMORY_SCOPE_AGENT);
}

// ---------------- pre-loop kernels ----------------

__global__ __launch_bounds__(256) void k_gather(const int* __restrict__ gt,
    const float* __restrict__ emb, float* __restrict__ Xall){
  int r = blockIdx.x;                 // r = t*32 + b
  int t = r >> 5, b = r & 31;
  int tok = gt[b*Tn + t];
  const float* src = emb + (size_t)tok*En;
  float* dst = Xall + (size_t)r*En;
  for (int i = threadIdx.x; i < En; i += 256) dst[i] = src[i];
}

// Zx = Xall @ Wk + bias   [3200,512]@[512,1024], f32 tiled 64x64
__global__ __launch_bounds__(256) void k_zx(const float* __restrict__ X,
    const float* __restrict__ Wk, const float* __restrict__ bias, float* __restrict__ Zx){
  __shared__ float As[64][17];
  __shared__ float Bs[16][65];
  int r0 = blockIdx.x * 64;
  int c0 = blockIdx.y * 64;
  int tid = threadIdx.x;
  int ty = tid >> 4, tx = tid & 15;
  float acc[4][4] = {};
  for (int k0 = 0; k0 < En; k0 += 16){
    #pragma unroll
    for (int p = 0; p < 4; ++p){
      int row = (tid>>4) + p*16, kk = tid & 15;
      As[row][kk] = X[(size_t)(r0+row)*En + k0 + kk];
    }
    #pragma unroll
    for (int p = 0; p < 4; ++p){
      int kk = (tid>>6) + p*4, cc = tid & 63;
      Bs[kk][cc] = Wk[(size_t)(k0+kk)*Z4n + c0 + cc];
    }
    __syncthreads();
    #pragma unroll
    for (int kk = 0; kk < 16; ++kk){
      float av[4], bv[4];
      #pragma unroll
      for (int i=0;i<4;++i) av[i] = As[ty*4+i][kk];
      #pragma unroll
      for (int j=0;j<4;++j) bv[j] = Bs[kk][tx*4+j];
      #pragma unroll
      for (int i=0;i<4;++i)
        #pragma unroll
        for (int j=0;j<4;++j) acc[i][j] += av[i]*bv[j];
    }
    __syncthreads();
  }
  #pragma unroll
  for (int i=0;i<4;++i){
    int row = r0 + ty*4 + i;
    #pragma unroll
    for (int j=0;j<4;++j){
      int col = c0 + tx*4 + j;
      Zx[(size_t)row*Z4n + col] = acc[i][j] + bias[col];
    }
  }
}

// gpx[t,:] = x[t,b=0,:] @ gp_Wi + gp_bi
__global__ __launch_bounds__(256) void k_gpx(const float* __restrict__ Xall,
    const float* __restrict__ Wi, const float* __restrict__ bi, float* __restrict__ gpx){
  int t = blockIdx.x, j = threadIdx.x;
  const float* x = Xall + (size_t)(t*Bn + 0)*En;
  float acc = bi[j];
  for (int u = 0; u < En; ++u) acc += x[u]*Wi[u*GPn + j];
  gpx[t*GPn + j] = acc;
}

// W2 [256][32000] f32 -> W2T [32000][256] bf16 (LDS-tiled transpose)
__global__ __launch_bounds__(256) void k_w2t(const float* __restrict__ W2,
    ushort_t* __restrict__ W2T){
  __shared__ float tile[64][65];
  int n0 = blockIdx.x * 64;   // 500
  int k0 = blockIdx.y * 64;   // 4
  int tx = threadIdx.x & 63, ty4 = threadIdx.x >> 6;
  #pragma unroll
  for (int i = 0; i < 16; ++i){
    int k = ty4 + i*4;
    tile[k][tx] = W2[(size_t)(k0+k)*Vn + n0 + tx];
  }
  __syncthreads();
  #pragma unroll
  for (int i = 0; i < 16; ++i){
    int n = ty4 + i*4;
    W2T[(size_t)(n0+n)*Un + k0 + tx] = f2bf(tile[tx][n]);
  }
}

// ---------------- persistent 256-block recurrent kernel ----------------
// b = blockIdx&31, k = blockIdx>>5. ONE flag per step. Deferred softmax:
// block k owns s-rows [50k,50k+50) with LOCAL cov + unnormalized exp; the
// 8 partial sums (spart) published at the step flag are consumed next step.
// Per step: 1 poll + 1 consolidated load phase {h, Sum decp, spart, Zx} +
// LSTM chain + early stores {h(t+1), decp(t+1)} + scores (overlap store-ack)
// + spart store + flag.

__global__ __launch_bounds__(1024, 1) void k_loop(
    const float* __restrict__ Zx, const float* __restrict__ Wr,
    const float* __restrict__ Wd, const float* __restrict__ bd,
    const float* __restrict__ Wc, const float* __restrict__ Wa,
    const float* __restrict__ enc_attn,
    const float* __restrict__ h0, const float* __restrict__ c0,
    float* __restrict__ h_all, float* __restrict__ decp,
    float* __restrict__ c0_all, float* __restrict__ a_all,
    float* __restrict__ covloss, float* __restrict__ spart,
    unsigned* __restrict__ bars){
  __shared__ float Wr_lds[256*128];     // 128 KB: Wr cols {32k+i+256q}
  __shared__ float hfull[Un];
  __shared__ float ppart[8][132];
  __shared__ float zx_lds[128];
  __shared__ float zfull[128];
  __shared__ float hnew[32], cown[32];
  __shared__ float dec_lds[AUn];
  __shared__ float cov_lds[50], sc_lds[50];
  __shared__ float wred[16];
  __shared__ float red8[8];

  const int b = blockIdx.x & 31, k = blockIdx.x >> 5;
  const int tid = threadIdx.x, lane = tid & 63, w = tid >> 6;
  unsigned* flags = bars + b*8*32;          // 8 slots, 128 B apart
  unsigned* myflag = flags + k*32;

  for (int idx = tid; idx < 256*128; idx += 1024){
    int u = idx >> 7, jl = idx & 127;
    int gcol = 32*k + (jl & 31) + 256*(jl >> 5);
    Wr_lds[idx] = Wr[(size_t)u*Z4n + gcol];
  }
  if (tid < 32) cown[tid] = c0[b*Un + 32*k + tid];
  if (tid < 50) cov_lds[tid] = 0.f;
  const float4 wc4 = *(const float4*)(Wc + lane*4);
  const float4 wa4 = *(const float4*)(Wa + lane*4);
  if (tid < 256) hfull[tid] = h0[b*Un + tid];
  if (tid >= 256 && tid < 384){
    int jl = tid - 256;
    int gcol = 32*k + (jl & 31) + 256*(jl >> 5);
    zx_lds[jl] = Zx[(size_t)(0*Bn + b)*Z4n + gcol];
  }
  __syncthreads();

  // ======== prestep: h(0), c(0), decp(0), flag = 1 ========
  {
    int p = tid >> 7, jl = tid & 127;
    float acc = 0.f;
    const float* wr = Wr_lds + (p*32)*128 + jl;
    const float* hb = hfull + p*32;
    #pragma unroll 8
    for (int uu = 0; uu < 32; ++uu) acc += hb[uu]*wr[uu*128];
    ppart[p][jl] = acc;
  }
  __syncthreads();
  if (tid < 128){
    float s = zx_lds[tid];
    #pragma unroll
    for (int q = 0; q < 8; ++q) s += ppart[q][tid];
    zfull[tid] = s;
  }
  __syncthreads();
  if (tid < 32){
    float zi = zfull[tid], zf = zfull[32+tid], zg = zfull[64+tid], zo = zfull[96+tid];
    float cn = sigmoid_f(zf)*cown[tid] + sigmoid_f(zi)*tanhf(zg);
    float hn = sigmoid_f(zo)*tanhf(cn);
    cown[tid] = cn; hnew[tid] = hn;
    int col = 32*k + tid;
    st_rlx(h_all + (size_t)(0*Bn + b)*Un + col, hn);
    if (b == 0) c0_all[0*Un + col] = cn;
  }
  __syncthreads();
  if (tid < 256){
    int c = tid;
    float acc = 0.f;
    const float* wdh = Wd + (size_t)(32*k)*AUn + c;
    #pragma unroll 8
    for (int u = 0; u < 32; ++u) acc += hnew[u]*wdh[(size_t)u*AUn];
    const float* wdc = Wd + (size_t)(Un + 32*k)*AUn + c;
    #pragma unroll 8
    for (int u = 0; u < 32; ++u) acc += cown[u]*wdc[(size_t)u*AUn];
    st_rlx(decp + (size_t)(b*8 + k)*256 + c, acc);   // slot 0
  }
  __syncthreads();    // drains vmcnt: stores acknowledged
  if (tid == 0) st_flag(myflag, 1u);

  // ======== main loop ========
  for (int t = 0; t < Tn; ++t){
    const int cur = t & 1, oth = cur ^ 1;
    // P0: wait (covers h(t), decp(t), spart(t-1))
    if (tid < 8){
      while (ld_flag(flags + tid*32) < (unsigned)(t+1))
        __builtin_amdgcn_s_sleep(1);
    }
    __syncthreads();
    // P1: all cross-block loads, one latency
    if (tid < 256){
      hfull[tid] = ld_rlx(h_all + (size_t)(t*Bn + b)*Un + tid);
    } else if (tid < 512){
      int c = tid - 256;
      float s = bd[c];
      const float* dp = decp + (size_t)cur*(Bn*8*256) + (size_t)(b*8)*256 + c;
      #pragma unroll
      for (int q = 0; q < 8; ++q) s += ld_rlx(dp + q*256);
      dec_lds[c] = s;
    } else if (tid < 520){
      red8[tid-512] = (t > 0) ? ld_rlx(spart + oth*(Bn*8) + b*8 + (tid-512)) : 0.f;
    } else if (tid >= 576 && tid < 704 && t + 1 < Tn){
      int jl = tid - 576;
      int gcol = 32*k + (jl & 31) + 256*(jl >> 5);
      zx_lds[jl] = Zx[(size_t)((t+1)*Bn + b)*Z4n + gcol];
    }
    __syncthreads();
    // P2: softmax-finish(t-1) on wave 0 ; LSTM partials on all waves
    if (t > 0 && w == 0){
      float pv = (lane < 8) ? red8[lane] : 0.f;
      pv += __shfl_xor(pv, 1); pv += __shfl_xor(pv, 2); pv += __shfl_xor(pv, 4);
      float inv = 1.f / __shfl(pv, 0);
      float clp = 0.f;
      if (lane < 50){
        float aa = sc_lds[lane] * inv;
        float co = cov_lds[lane];
        a_all[(size_t)((t-1)*Bn + b)*Sn + 50*k + lane] = aa;
        clp = fminf(co, aa);
        cov_lds[lane] = co + aa;
      }
      #pragma unroll
      for (int m = 1; m < 64; m <<= 1) clp += __shfl_xor(clp, m);
      if (lane == 0) atomicAdd(&covloss[b*Tn + (t-1)], clp);
    }
    {
      int p = tid >> 7, jl = tid & 127;
      float acc = 0.f;
      const float* wr = Wr_lds + (p*32)*128 + jl;
      const float* hb = hfull + p*32;
      #pragma unroll 8
      for (int uu = 0; uu < 32; ++uu) acc += hb[uu]*wr[uu*128];
      ppart[p][jl] = acc;
    }
    __syncthreads();
    // P3: z reduce
    if (tid < 128 && t + 1 < Tn){
      float s = zx_lds[tid];
      #pragma unroll
      for (int q = 0; q < 8; ++q) s += ppart[q][tid];
      zfull[tid] = s;
    }
    __syncthreads();
    // P4: gates + h(t+1)/c publish
    if (tid < 32 && t + 1 < Tn){
      float zi = zfull[tid], zf = zfull[32+tid], zg = zfull[64+tid], zo = zfull[96+tid];
      float cn = sigmoid_f(zf)*cown[tid] + sigmoid_f(zi)*tanhf(zg);
      float hn = sigmoid_f(zo)*tanhf(cn);
      cown[tid] = cn; hnew[tid] = hn;
      int col = 32*k + tid;
      st_rlx(h_all + (size_t)((t+1)*Bn + b)*Un + col, hn);
      if (b == 0) c0_all[(t+1)*Un + col] = cn;
    }
    __syncthreads();
    // P5: decp(t+1) on waves 0-3 ; scores(t) on waves 4-15 (overlaps store-ack)
    if (w < 4){
      if (t + 1 < Tn){
        int c = tid;
        float acc = 0.f;
        const float* wdh = Wd + (size_t)(32*k)*AUn + c;
        #pragma unroll 8
        for (int u = 0; u < 32; ++u) acc += hnew[u]*wdh[(size_t)u*AUn];
        const float* wdc = Wd + (size_t)(Un + 32*k)*AUn + c;
        #pragma unroll 8
        for (int u = 0; u < 32; ++u) acc += cown[u]*wdc[(size_t)u*AUn];
        st_rlx(decp + (size_t)oth*(Bn*8*256) + (size_t)(b*8 + k)*256 + c, acc);
      }
    } else {
      const float4 da = *(const float4*)(dec_lds + lane*4);
      float wsum = 0.f;
      for (int sl = w - 4; sl < 50; sl += 12){
        float cvv = cov_lds[sl];
        const float4 e = *(const float4*)(enc_attn + ((size_t)(b*Sn + 50*k + sl))*AUn + lane*4);
        float psc = tanh_fast(e.x + cvv*wc4.x + da.x)*wa4.x
                  + tanh_fast(e.y + cvv*wc4.y + da.y)*wa4.y
                  + tanh_fast(e.z + cvv*wc4.z + da.z)*wa4.z
                  + tanh_fast(e.w + cvv*wc4.w + da.w)*wa4.w;
        #pragma unroll
        for (int m = 1; m < 64; m <<= 1) psc += __shfl_xor(psc, m);
        if (lane == 0){
          float ev = __expf(psc);
          sc_lds[sl] = ev;
          wsum += ev;
        }
      }
      if (lane == 0) wred[w] = wsum;
    }
    __syncthreads();
    // P6: spart publish + flag
    if (tid == 0){
      float S = 0.f;
      #pragma unroll
      for (int q = 4; q < 16; ++q) S += wred[q];
      st_rlx(spart + cur*(Bn*8) + b*8 + k, S);
    }
    __syncthreads();    // drains all stores (incl. spart) before flag
    if (tid == 0) st_flag(myflag, (unsigned)(t + 2));
  }

  // ======== post-loop: softmax-finish(Tn-1) ========
  if (tid < 8){
    while (ld_flag(flags + tid*32) < (unsigned)(Tn + 1))
      __builtin_amdgcn_s_sleep(1);
  }
  __syncthreads();
  if (tid < 8) red8[tid] = ld_rlx(spart + ((Tn-1)&1)*(Bn*8) + b*8 + tid);
  __syncthreads();
  if (w == 0){
    float pv = (lane < 8) ? red8[lane] : 0.f;
    pv += __shfl_xor(pv, 1); pv += __shfl_xor(pv, 2); pv += __shfl_xor(pv, 4);
    float inv = 1.f / __shfl(pv, 0);
    float clp = 0.f;
    if (lane < 50){
      float aa = sc_lds[lane] * inv;
      float co = cov_lds[lane];
      a_all[(size_t)((Tn-1)*Bn + b)*Sn + 50*k + lane] = aa;
      clp = fminf(co, aa);
    }
    #pragma unroll
    for (int m = 1; m < 64; m <<= 1) clp += __shfl_xor(clp, m);
    if (lane == 0) atomicAdd(&covloss[b*Tn + (Tn-1)], clp);
  }
}

// ---------------- post-loop kernels ----------------

// hid = h_all @ W1 + b1 -> bf16    (block per t)
__global__ __launch_bounds__(256) void k_hid(const float* __restrict__ h_all,
    const float* __restrict__ W1, const float* __restrict__ b1, ushort_t* __restrict__ hid){
  __shared__ float hl[Bn*Un];
  int t = blockIdx.x, tid = threadIdx.x;
  for (int i = tid; i < Bn*Un; i += 256) hl[i] = h_all[(size_t)t*Bn*Un + i];
  __syncthreads();
  int j = tid;
  float bj = b1[j];
  float acc[32];
  #pragma unroll
  for (int r = 0; r < 32; ++r) acc[r] = bj;
  for (int u = 0; u < Un; ++u){
    float wv = W1[u*Un + j];
    #pragma unroll
    for (int r = 0; r < 32; ++r) acc[r] += hl[r*Un + u]*wv;
  }
  #pragma unroll
  for (int r = 0; r < 32; ++r) hid[(size_t)(t*Bn + r)*Un + j] = f2bf(acc[r]);
}

// pg[t] via row-0 quirk
__global__ __launch_bounds__(256) void k_pg(const float* __restrict__ a_all,
    const float* __restrict__ enc_out, const float* __restrict__ h_all,
    const float* __restrict__ c0_all, const float* __restrict__ gpWs,
    const float* __restrict__ gpWc, const float* __restrict__ gpx,
    const float* __restrict__ gpWg, float* __restrict__ pg){
  __shared__ float al[Sn];
  __shared__ float cv[ENCn];
  __shared__ float red[4];
  int t = blockIdx.x, tid = threadIdx.x;
  for (int s = tid; s < Sn; s += 256) al[s] = a_all[(size_t)(t*Bn + 0)*Sn + s];
  __syncthreads();
  for (int e = tid; e < ENCn; e += 256){
    float acc = 0.f;
    for (int s = 0; s < Sn; ++s) acc += enc_out[(size_t)s*ENCn + e]*al[s];
    cv[e] = acc;
  }
  __syncthreads();
  int j = tid;
  float g = gpx[t*GPn + j];
  const float* h0r = h_all + (size_t)t*Bn*Un;       // b = 0 row
  const float* c0r = c0_all + t*Un;
  for (int u = 0; u < Un; ++u) g += h0r[u]*gpWs[u*GPn + j];
  for (int u = 0; u < Un; ++u) g += c0r[u]*gpWs[(Un+u)*GPn + j];
  for (int e = 0; e < ENCn; ++e) g += cv[e]*gpWc[e*GPn + j];
  float v = g * gpWg[j];
  int lane = tid & 63, wv2 = tid >> 6;
  #pragma unroll
  for (int m = 1; m < 64; m <<= 1) v += __shfl_xor(v, m);
  if (lane == 0) red[wv2] = v;
  __syncthreads();
  if (tid == 0) pg[t] = 1.f/(1.f+__expf(-(red[0]+red[1]+red[2]+red[3])));
}

// GEMM: A = hid [3200][256] bf16, B = W2T [32000][256] bf16.
// mode 0: Ssum[r] += sum_v exp(logit);  mode 1: probs = pg*exp/S (+OOV zeros) + amax
__global__ __launch_bounds__(256) void k_gemm(const ushort_t* __restrict__ A,
    const ushort_t* __restrict__ Bw, const float* __restrict__ b2,
    float* __restrict__ Ssum, u64* __restrict__ amax, const float* __restrict__ pg,
    float* __restrict__ probs, int mode){
  int r0 = blockIdx.x * 64;
  int n0 = blockIdx.y * 256;
  int tid = threadIdx.x;
  if (mode == 1 && n0 >= Vn){
    for (int idx = tid; idx < 64*OOVn; idx += 256){
      int i = idx/OOVn, vv = idx%OOVn;
      int r = r0+i; int tt = r>>5, bb = r&31;
      probs[(size_t)(bb*Tn+tt)*VEn + Vn + vv] = 0.f;
    }
    return;
  }
  __shared__ ushort_t Bs[64*264];          // [64 n][256 k + pad8]
  int lane = tid & 63, w = tid >> 6;
  bf16x8 af[8];
  {
    const ushort_t* ar = A + (size_t)(r0 + w*16 + (lane&15))*Un + (lane>>4)*8;
    #pragma unroll
    for (int kk = 0; kk < 8; ++kk) af[kk] = *(const bf16x8*)(ar + kk*32);
  }
  f32x4 acc[16];
  #pragma unroll
  for (int i = 0; i < 16; ++i) acc[i] = (f32x4){0.f,0.f,0.f,0.f};

  for (int nsub = 0; nsub < 4; ++nsub){
    __syncthreads();
    {
      const ushort_t* gb = Bw + (size_t)(n0 + nsub*64)*Un;
      #pragma unroll
      for (int i = 0; i < 8; ++i){
        int chunk = tid + i*256;
        int rr = chunk >> 5, cc = chunk & 31;
        uint4 d = *(const uint4*)(gb + rr*Un + cc*8);
        *(uint4*)(Bs + rr*264 + cc*8) = d;
      }
    }
    __syncthreads();
    #pragma unroll
    for (int kk = 0; kk < 8; ++kk){
      #pragma unroll
      for (int ntl = 0; ntl < 4; ++ntl){
        bf16x8 bf = *(const bf16x8*)(Bs + (ntl*16 + (lane&15))*264 + kk*32 + (lane>>4)*8);
        acc[nsub*4+ntl] = __builtin_amdgcn_mfma_f32_16x16x32_bf16(af[kk], bf, acc[nsub*4+ntl], 0, 0, 0);
      }
    }
  }

  int rowloc = w*16 + (lane>>4)*4;
  if (mode == 0){
    float rs[4] = {0.f,0.f,0.f,0.f};
    #pragma unroll
    for (int nt = 0; nt < 16; ++nt){
      int v = n0 + (nt>>2)*64 + (nt&3)*16 + (lane&15);
      float bb = b2[v];
      #pragma unroll
      for (int i = 0; i < 4; ++i) rs[i] += __expf(acc[nt][i] + bb);
    }
    #pragma unroll
    for (int m = 1; m < 16; m <<= 1)
      #pragma unroll
      for (int i = 0; i < 4; ++i) rs[i] += __shfl_xor(rs[i], m);
    if ((lane&15) == 0)
      #pragma unroll
      for (int i = 0; i < 4; ++i) atomicAdd(&Ssum[r0+rowloc+i], rs[i]);
  } else {
    float sc[4]; size_t obase[4];
    #pragma unroll
    for (int i = 0; i < 4; ++i){
      int r = r0+rowloc+i; int tt = r>>5, bb = r&31;
      sc[i] = pg[tt] / Ssum[r];
      obase[i] = (size_t)(bb*Tn+tt)*VEn;
    }
    u64 pm[4] = {0,0,0,0};
    #pragma unroll
    for (int nt = 0; nt < 16; ++nt){
      int v = n0 + (nt>>2)*64 + (nt&3)*16 + (lane&15);
      float bb = b2[v];
      #pragma unroll
      for (int i = 0; i < 4; ++i){
        float val = __expf(acc[nt][i] + bb) * sc[i];
        probs[obase[i] + v] = val;
        u64 p = ((u64)__float_as_uint(val)<<32) | (u64)(0xFFFFFFFFu - (unsigned)v);
        pm[i] = p > pm[i] ? p : pm[i];
      }
    }
    #pragma unroll
    for (int m = 1; m < 16; m <<= 1)
      #pragma unroll
      for (int i = 0; i < 4; ++i){
        u64 o = shfl_xor_u64(pm[i], m);
        pm[i] = o > pm[i] ? o : pm[i];
      }
    if ((lane&15) == 0)
      #pragma unroll
      for (int i = 0; i < 4; ++i) atomicMax(&amax[r0+rowloc+i], pm[i]);
  }
}

// scatter copy-dist into probs (deduped single-writer) + update amax
__global__ __launch_bounds__(256) void k_scatter(const int* __restrict__ ext,
    const float* __restrict__ a_all, const float* __restrict__ pg,
    float* __restrict__ probs, u64* __restrict__ amax){
  __shared__ int tok[Sn];
  __shared__ float val[Sn];
  int r = blockIdx.x; int t = r>>5, b = r&31;
  float c1 = 1.f - pg[t];
  int tid = threadIdx.x;
  for (int s = tid; s < Sn; s += 256){
    tok[s] = ext[b*Sn + s];
    val[s] = c1 * a_all[(size_t)r*Sn + s];
  }
  __syncthreads();
  size_t obase = (size_t)(b*Tn + t)*VEn;
  for (int s = tid; s < Sn; s += 256){
    int tk = tok[s];
    bool leader = true;
    float tot = 0.f;
    for (int s2 = 0; s2 < Sn; ++s2){
      if (tok[s2] == tk){
        if (s2 < s){ leader = false; break; }
        tot += val[s2];
      }
    }
    if (leader){
      float nv = probs[obase + tk] + tot;
      probs[obase + tk] = nv;
      u64 p = ((u64)__float_as_uint(nv)<<32) | (u64)(0xFFFFFFFFu - (unsigned)tk);
      atomicMax(&amax[r], p);
    }
  }
}

__global__ __launch_bounds__(256) void k_seqout(const u64* __restrict__ amax,
    float* __restrict__ seqs){
  int r = blockIdx.x*256 + threadIdx.x;
  if (r >= Tn*Bn) return;
  int t = r>>5, b = r&31;
  unsigned tk = 0xFFFFFFFFu - (unsigned)(amax[r] & 0xFFFFFFFFull);
  seqs[b*Tn + t] = (float)tk;
}

// ---------------- host launch ----------------

extern "C" void kernel_launch(void* const* d_in, const int* in_sizes, int n_in,
                              void* d_out, int out_size, void* d_ws, size_t ws_size,
                              hipStream_t stream){
  (void)in_sizes; (void)n_in; (void)out_size; (void)ws_size;
  const int*   gt       = (const int*)d_in[0];
  const int*   ext      = (const int*)d_in[1];
  const float* enc_out  = (const float*)d_in[2];
  const float* enc_attn = (const float*)d_in[3];
  const float* h0       = (const float*)d_in[4];
  const float* c0       = (const float*)d_in[5];
  const float* emb      = (const float*)d_in[6];
  const float* Wk       = (const float*)d_in[7];
  const float* Wr       = (const float*)d_in[8];
  const float* lb       = (const float*)d_in[9];
  const float* Wd       = (const float*)d_in[10];
  const float* bd       = (const float*)d_in[11];
  const float* Wc       = (const float*)d_in[12];
  const float* Wa       = (const float*)d_in[13];
  const float* W1       = (const float*)d_in[14];
  const float* b1       = (const float*)d_in[15];
  const float* W2       = (const float*)d_in[16];
  const float* b2       = (const float*)d_in[17];
  const float* gpWs     = (const float*)d_in[18];
  const float* gpWc     = (const float*)d_in[19];
  const float* gpWi     = (const float*)d_in[20];
  const float* gpbi     = (const float*)d_in[21];
  const float* gpWg     = (const float*)d_in[22];

  float* probs   = (float*)d_out;
  float* seqs    = probs + (size_t)Bn*Tn*VEn;
  float* covloss = seqs + Bn*Tn;

  char* wp = (char*)d_ws;
  auto carve = [&](size_t bytes)->void*{
    void* p = (void*)wp; wp += (bytes + 255) & ~(size_t)255; return p;
  };
  float*    Xall    = (float*)carve((size_t)3200*En*4);
  float*    Zx      = (float*)carve((size_t)3200*Z4n*4);
  float*    gpx     = (float*)carve((size_t)Tn*GPn*4);
  float*    h_all   = (float*)carve((size_t)Tn*Bn*Un*4);
  float*    decp    = (float*)carve((size_t)2*Bn*8*256*4);
  float*    c0_all  = (float*)carve((size_t)Tn*Un*4);
  float*    a_all   = (float*)carve((size_t)3200*Sn*4);
  ushort_t* hid_bf  = (ushort_t*)carve((size_t)3200*Un*2);
  ushort_t* W2T     = (ushort_t*)carve((size_t)Vn*Un*2);
  float*    Ssum    = (float*)carve((size_t)3200*4);
  u64*      amax    = (u64*)carve((size_t)3200*8);
  float*    pg      = (float*)carve((size_t)Tn*4);
  float*    spart   = (float*)carve((size_t)2*Bn*8*4);
  unsigned* bars    = (unsigned*)carve((size_t)Bn*8*32*4);

  hipMemsetAsync(Ssum, 0, 3200*4, stream);
  hipMemsetAsync(amax, 0, 3200*8, stream);
  hipMemsetAsync(bars, 0, Bn*8*32*4, stream);
  hipMemsetAsync(covloss, 0, Bn*Tn*4, stream);

  k_gather<<<3200, 256, 0, stream>>>(gt, emb, Xall);
  k_zx    <<<dim3(50,16), 256, 0, stream>>>(Xall, Wk, lb, Zx);

  k_loop  <<<256, 1024, 0, stream>>>(Zx, Wr, Wd, bd, Wc, Wa, enc_attn,
                                     h0, c0, h_all, decp, c0_all,
                                     a_all, covloss, spart, bars);

  k_w2t <<<dim3(500,4), 256, 0, stream>>>(W2, W2T);
  k_gpx <<<Tn, 256, 0, stream>>>(Xall, gpWi, gpbi, gpx);
  k_hid <<<Tn, 256, 0, stream>>>(h_all, W1, b1, hid_bf);
  k_pg  <<<Tn, 256, 0, stream>>>(a_all, enc_out, h_all, c0_all, gpWs, gpWc, gpx, gpWg, pg);
  k_gemm<<<dim3(50,125), 256, 0, stream>>>(hid_bf, W2T, b2, Ssum, amax, pg, probs, 0);
  k_gemm<<<dim3(50,126), 256, 0, stream>>>(hid_bf, W2T, b2, Ssum, amax, pg, probs, 1);
  k_scatter<<<3200, 256, 0, stream>>>(ext, a_all, pg, probs, amax);
  k_seqout <<<13, 256, 0, stream>>>(amax, seqs);
}

// Round 8
// 1342.816 us; speedup vs baseline: 1.2362x; 1.0092x over previous
//
#include <hip/hip_runtime.h>
#include <hip/hip_bf16.h>

#define Bn 32
#define Sn 400
#define Tn 100
#define Vn 32000
#define OOVn 100
#define VEn 32100
#define En 512
#define Un 256
#define AUn 256
#define GPn 256
#define ENCn 512
#define Z4n 1024

typedef __attribute__((ext_vector_type(8))) short bf16x8;
typedef __attribute__((ext_vector_type(4))) float f32x4;
typedef unsigned short ushort_t;
typedef unsigned long long u64;

__device__ __forceinline__ float rcp_f(float x){ return __builtin_amdgcn_rcpf(x); }
__device__ __forceinline__ float tanh_fast(float x){
  float e2 = __expf(2.f*x);
  return 1.f - 2.f*rcp_f(e2 + 1.f);
}
__device__ __forceinline__ float sigmoid_f(float x){ return 1.f/(1.f+__expf(-x)); }
__device__ __forceinline__ ushort_t f2bf(float f){
  unsigned u = __float_as_uint(f);
  unsigned r = (u + 0x7FFFu + ((u>>16)&1u)) >> 16;   // RNE
  return (ushort_t)r;
}
__device__ __forceinline__ u64 shfl_xor_u64(u64 v, int m){
  unsigned lo = (unsigned)v, hi = (unsigned)(v>>32);
  lo = (unsigned)__shfl_xor((int)lo, m);
  hi = (unsigned)__shfl_xor((int)hi, m);
  return ((u64)hi<<32)|(u64)lo;
}

// relaxed agent-scope ops: coherence-point loads/stores, no cache maintenance
__device__ __forceinline__ void st_rlx(float* p, float v){
  __hip_atomic_store(p, v, __ATOMIC_RELAXED, __HIP_MEMORY_SCOPE_AGENT);
}
__device__ __forceinline__ float ld_rlx(const float* p){
  return __hip_atomic_load(p, __ATOMIC_RELAXED, __HIP_MEMORY_SCOPE_AGENT);
}
__device__ __forceinline__ void st_flag(unsigned* p, unsigned v){
  __hip_atomic_store(p, v, __ATOMIC_RELAXED, __HIP_MEMORY_SCOPE_AGENT);
}
__device__ __forceinline__ unsigned ld_flag(const unsigned* p){
  return __hip_atomic_load(p, __ATOMIC_RELAXED, __HIP_MEMORY_SCOPE_AGENT);
}

// ---------------- pre-loop kernels ----------------

__global__ __launch_bounds__(256) void k_gather(const int* __restrict__ gt,
    const float* __restrict__ emb, float* __restrict__ Xall){
  int r = blockIdx.x;                 // r = t*32 + b
  int t = r >> 5, b = r & 31;
  int tok = gt[b*Tn + t];
  const float* src = emb + (size_t)tok*En;
  float* dst = Xall + (size_t)r*En;
  for (int i = threadIdx.x; i < En; i += 256) dst[i] = src[i];
}

// Zx = Xall @ Wk + bias   [3200,512]@[512,1024], f32 tiled 64x64
__global__ __launch_bounds__(256) void k_zx(const float* __restrict__ X,
    const float* __restrict__ Wk, const float* __restrict__ bias, float* __restrict__ Zx){
  __shared__ float As[64][17];
  __shared__ float Bs[16][65];
  int r0 = blockIdx.x * 64;
  int c0 = blockIdx.y * 64;
  int tid = threadIdx.x;
  int ty = tid >> 4, tx = tid & 15;
  float acc[4][4] = {};
  for (int k0 = 0; k0 < En; k0 += 16){
    #pragma unroll
    for (int p = 0; p < 4; ++p){
      int row = (tid>>4) + p*16, kk = tid & 15;
      As[row][kk] = X[(size_t)(r0+row)*En + k0 + kk];
    }
    #pragma unroll
    for (int p = 0; p < 4; ++p){
      int kk = (tid>>6) + p*4, cc = tid & 63;
      Bs[kk][cc] = Wk[(size_t)(k0+kk)*Z4n + c0 + cc];
    }
    __syncthreads();
    #pragma unroll
    for (int kk = 0; kk < 16; ++kk){
      float av[4], bv[4];
      #pragma unroll
      for (int i=0;i<4;++i) av[i] = As[ty*4+i][kk];
      #pragma unroll
      for (int j=0;j<4;++j) bv[j] = Bs[kk][tx*4+j];
      #pragma unroll
      for (int i=0;i<4;++i)
        #pragma unroll
        for (int j=0;j<4;++j) acc[i][j] += av[i]*bv[j];
    }
    __syncthreads();
  }
  #pragma unroll
  for (int i=0;i<4;++i){
    int row = r0 + ty*4 + i;
    #pragma unroll
    for (int j=0;j<4;++j){
      int col = c0 + tx*4 + j;
      Zx[(size_t)row*Z4n + col] = acc[i][j] + bias[col];
    }
  }
}

// gpx[t,:] = x[t,b=0,:] @ gp_Wi + gp_bi
__global__ __launch_bounds__(256) void k_gpx(const float* __restrict__ Xall,
    const float* __restrict__ Wi, const float* __restrict__ bi, float* __restrict__ gpx){
  int t = blockIdx.x, j = threadIdx.x;
  const float* x = Xall + (size_t)(t*Bn + 0)*En;
  float acc = bi[j];
  for (int u = 0; u < En; ++u) acc += x[u]*Wi[u*GPn + j];
  gpx[t*GPn + j] = acc;
}

// W2 [256][32000] f32 -> W2T [32000][256] bf16 (LDS-tiled transpose)
__global__ __launch_bounds__(256) void k_w2t(const float* __restrict__ W2,
    ushort_t* __restrict__ W2T){
  __shared__ float tile[64][65];
  int n0 = blockIdx.x * 64;   // 500
  int k0 = blockIdx.y * 64;   // 4
  int tx = threadIdx.x & 63, ty4 = threadIdx.x >> 6;
  #pragma unroll
  for (int i = 0; i < 16; ++i){
    int k = ty4 + i*4;
    tile[k][tx] = W2[(size_t)(k0+k)*Vn + n0 + tx];
  }
  __syncthreads();
  #pragma unroll
  for (int i = 0; i < 16; ++i){
    int n = ty4 + i*4;
    W2T[(size_t)(n0+n)*Un + k0 + tx] = f2bf(tile[tx][n]);
  }
}

// ---------------- persistent 256-block recurrent kernel ----------------
// b = blockIdx&31, k = blockIdx>>5. ONE flag/step, 5 barriers/step.
// Deferred softmax; per-wave score-sum partials (spart2, 12/block) published
// directly from P4, consumed as 96 values next step by wave 0.

__global__ __launch_bounds__(1024, 1) void k_loop(
    const float* __restrict__ Zx, const float* __restrict__ Wr,
    const float* __restrict__ Wd, const float* __restrict__ bd,
    const float* __restrict__ Wc, const float* __restrict__ Wa,
    const float* __restrict__ enc_attn,
    const float* __restrict__ h0, const float* __restrict__ c0,
    float* __restrict__ h_all, float* __restrict__ decp,
    float* __restrict__ c0_all, float* __restrict__ a_all,
    float* __restrict__ covloss, float* __restrict__ spart2,
    unsigned* __restrict__ bars){
  __shared__ float Wr_lds[256*128];     // 128 KB: Wr cols {32k+i+256q}
  __shared__ float hfull[Un];
  __shared__ float ppart[8][132];
  __shared__ float zx_lds[128];
  __shared__ float hnew[32], cown[32];
  __shared__ float dec_lds[AUn];
  __shared__ float cov_lds[50], sc_lds[50];
  __shared__ float red96[96];

  const int b = blockIdx.x & 31, k = blockIdx.x >> 5;
  const int tid = threadIdx.x, lane = tid & 63, w = tid >> 6;
  unsigned* flags = bars + b*8*32;          // 8 slots, 128 B apart
  unsigned* myflag = flags + k*32;

  for (int idx = tid; idx < 256*128; idx += 1024){
    int u = idx >> 7, jl = idx & 127;
    int gcol = 32*k + (jl & 31) + 256*(jl >> 5);
    Wr_lds[idx] = Wr[(size_t)u*Z4n + gcol];
  }
  if (tid < 32) cown[tid] = c0[b*Un + 32*k + tid];
  if (tid < 50) cov_lds[tid] = 0.f;
  const float4 wc4 = *(const float4*)(Wc + lane*4);
  const float4 wa4 = *(const float4*)(Wa + lane*4);
  if (tid < 256) hfull[tid] = h0[b*Un + tid];
  if (tid >= 256 && tid < 384){
    int jl = tid - 256;
    int gcol = 32*k + (jl & 31) + 256*(jl >> 5);
    zx_lds[jl] = Zx[(size_t)(0*Bn + b)*Z4n + gcol];
  }
  __syncthreads();

  // ======== prestep: h(0), c(0), decp slot0, flag = 1 ========
  {
    int p = tid >> 7, jl = tid & 127;
    float acc = 0.f;
    const float* wr = Wr_lds + (p*32)*128 + jl;
    const float* hb = hfull + p*32;
    #pragma unroll 8
    for (int uu = 0; uu < 32; ++uu) acc += hb[uu]*wr[uu*128];
    ppart[p][jl] = acc;
  }
  __syncthreads();
  if (tid < 32){
    float zi = zx_lds[tid], zf = zx_lds[32+tid], zg = zx_lds[64+tid], zo = zx_lds[96+tid];
    #pragma unroll
    for (int q = 0; q < 8; ++q){
      zi += ppart[q][tid]; zf += ppart[q][32+tid];
      zg += ppart[q][64+tid]; zo += ppart[q][96+tid];
    }
    float cn = sigmoid_f(zf)*cown[tid] + sigmoid_f(zi)*tanhf(zg);
    float hn = sigmoid_f(zo)*tanhf(cn);
    cown[tid] = cn; hnew[tid] = hn;
    int col = 32*k + tid;
    st_rlx(h_all + (size_t)(0*Bn + b)*Un + col, hn);
    if (b == 0) c0_all[0*Un + col] = cn;
  }
  __syncthreads();
  if (tid < 256){
    int c = tid;
    float acc = 0.f;
    const float* wdh = Wd + (size_t)(32*k)*AUn + c;
    #pragma unroll 8
    for (int u = 0; u < 32; ++u) acc += hnew[u]*wdh[(size_t)u*AUn];
    const float* wdc = Wd + (size_t)(Un + 32*k)*AUn + c;
    #pragma unroll 8
    for (int u = 0; u < 32; ++u) acc += cown[u]*wdc[(size_t)u*AUn];
    st_rlx(decp + (size_t)(b*8 + k)*256 + c, acc);   // slot 0
  }
  __syncthreads();    // drains vmcnt: stores acknowledged
  if (tid == 0) st_flag(myflag, 1u);

  // ======== main loop ========
  for (int t = 0; t < Tn; ++t){
    const int cur = t & 1, oth = cur ^ 1;
    // P0: wait (covers h(t), decp(t), spart2(t-1))
    if (tid < 8){
      while (ld_flag(flags + tid*32) < (unsigned)(t+1))
        __builtin_amdgcn_s_sleep(1);
    }
    __syncthreads();
    // P1: all cross-block loads in one latency window
    if (tid < 256){
      hfull[tid] = ld_rlx(h_all + (size_t)(t*Bn + b)*Un + tid);
    } else if (tid < 512){
      int c = tid - 256;
      float s = bd[c];
      const float* dp = decp + (size_t)cur*(Bn*8*256) + (size_t)(b*8)*256 + c;
      #pragma unroll
      for (int q = 0; q < 8; ++q) s += ld_rlx(dp + q*256);
      dec_lds[c] = s;
    } else if (tid < 608){
      int l = tid - 512;
      red96[l] = (t > 0) ? ld_rlx(spart2 + oth*(Bn*96) + b*96 + l) : 0.f;
    } else if (tid >= 640 && tid < 768 && t + 1 < Tn){
      int jl = tid - 640;
      int gcol = 32*k + (jl & 31) + 256*(jl >> 5);
      zx_lds[jl] = Zx[(size_t)((t+1)*Bn + b)*Z4n + gcol];
    }
    __syncthreads();
    // P2: softmax-finish(t-1) on wave 0 ; LSTM partials on all waves
    if (t > 0 && w == 0){
      float v = red96[lane] + (lane < 32 ? red96[64 + lane] : 0.f);
      #pragma unroll
      for (int m = 1; m < 64; m <<= 1) v += __shfl_xor(v, m);
      float inv = 1.f / v;
      float clp = 0.f;
      if (lane < 50){
        float aa = sc_lds[lane] * inv;
        float co = cov_lds[lane];
        a_all[(size_t)((t-1)*Bn + b)*Sn + 50*k + lane] = aa;
        clp = fminf(co, aa);
        cov_lds[lane] = co + aa;
      }
      #pragma unroll
      for (int m = 1; m < 64; m <<= 1) clp += __shfl_xor(clp, m);
      if (lane == 0) atomicAdd(&covloss[b*Tn + (t-1)], clp);
    }
    {
      int p = tid >> 7, jl = tid & 127;
      float acc = 0.f;
      const float* wr = Wr_lds + (p*32)*128 + jl;
      const float* hb = hfull + p*32;
      #pragma unroll 8
      for (int uu = 0; uu < 32; ++uu) acc += hb[uu]*wr[uu*128];
      ppart[p][jl] = acc;
    }
    __syncthreads();
    // P3: z-reduce + gates + h(t+1)/c publish (fused, 32 threads)
    if (tid < 32 && t + 1 < Tn){
      float zi = zx_lds[tid], zf = zx_lds[32+tid], zg = zx_lds[64+tid], zo = zx_lds[96+tid];
      #pragma unroll
      for (int q = 0; q < 8; ++q){
        zi += ppart[q][tid]; zf += ppart[q][32+tid];
        zg += ppart[q][64+tid]; zo += ppart[q][96+tid];
      }
      float cn = sigmoid_f(zf)*cown[tid] + sigmoid_f(zi)*tanhf(zg);
      float hn = sigmoid_f(zo)*tanhf(cn);
      cown[tid] = cn; hnew[tid] = hn;
      int col = 32*k + tid;
      st_rlx(h_all + (size_t)((t+1)*Bn + b)*Un + col, hn);
      if (b == 0) c0_all[(t+1)*Un + col] = cn;
    }
    __syncthreads();
    // P4: decp(t+1) on waves 0-3 ; scores(t) + per-wave spart2 on waves 4-15
    if (w < 4){
      if (t + 1 < Tn){
        int c = tid;
        float acc = 0.f;
        const float* wdh = Wd + (size_t)(32*k)*AUn + c;
        #pragma unroll 8
        for (int u = 0; u < 32; ++u) acc += hnew[u]*wdh[(size_t)u*AUn];
        const float* wdc = Wd + (size_t)(Un + 32*k)*AUn + c;
        #pragma unroll 8
        for (int u = 0; u < 32; ++u) acc += cown[u]*wdc[(size_t)u*AUn];
        st_rlx(decp + (size_t)oth*(Bn*8*256) + (size_t)(b*8 + k)*256 + c, acc);
      }
    } else {
      const float4 da = *(const float4*)(dec_lds + lane*4);
      float wsum = 0.f;
      for (int sl = w - 4; sl < 50; sl += 12){
        float cvv = cov_lds[sl];
        const float4 e = *(const float4*)(enc_attn + ((size_t)(b*Sn + 50*k + sl))*AUn + lane*4);
        float psc = tanh_fast(e.x + cvv*wc4.x + da.x)*wa4.x
                  + tanh_fast(e.y + cvv*wc4.y + da.y)*wa4.y
                  + tanh_fast(e.z + cvv*wc4.z + da.z)*wa4.z
                  + tanh_fast(e.w + cvv*wc4.w + da.w)*wa4.w;
        #pragma unroll
        for (int m = 1; m < 64; m <<= 1) psc += __shfl_xor(psc, m);
        if (lane == 0){
          float ev = __expf(psc);
          sc_lds[sl] = ev;
          wsum += ev;
        }
      }
      if (lane == 0)
        st_rlx(spart2 + cur*(Bn*96) + b*96 + k*12 + (w-4), wsum);
    }
    __syncthreads();    // drains all stores before flag
    if (tid == 0) st_flag(myflag, (unsigned)(t + 2));
  }

  // ======== post-loop: softmax-finish(Tn-1) ========
  if (tid < 8){
    while (ld_flag(flags + tid*32) < (unsigned)(Tn + 1))
      __builtin_amdgcn_s_sleep(1);
  }
  __syncthreads();
  if (tid < 96) red96[tid] = ld_rlx(spart2 + ((Tn-1)&1)*(Bn*96) + b*96 + tid);
  __syncthreads();
  if (w == 0){
    float v = red96[lane] + (lane < 32 ? red96[64 + lane] : 0.f);
    #pragma unroll
    for (int m = 1; m < 64; m <<= 1) v += __shfl_xor(v, m);
    float inv = 1.f / v;
    float clp = 0.f;
    if (lane < 50){
      float aa = sc_lds[lane] * inv;
      float co = cov_lds[lane];
      a_all[(size_t)((Tn-1)*Bn + b)*Sn + 50*k + lane] = aa;
      clp = fminf(co, aa);
    }
    #pragma unroll
    for (int m = 1; m < 64; m <<= 1) clp += __shfl_xor(clp, m);
    if (lane == 0) atomicAdd(&covloss[b*Tn + (Tn-1)], clp);
  }
}

// ---------------- post-loop kernels ----------------

// hid = h_all @ W1 + b1 -> bf16    (block per t)
__global__ __launch_bounds__(256) void k_hid(const float* __restrict__ h_all,
    const float* __restrict__ W1, const float* __restrict__ b1, ushort_t* __restrict__ hid){
  __shared__ float hl[Bn*Un];
  int t = blockIdx.x, tid = threadIdx.x;
  for (int i = tid; i < Bn*Un; i += 256) hl[i] = h_all[(size_t)t*Bn*Un + i];
  __syncthreads();
  int j = tid;
  float bj = b1[j];
  float acc[32];
  #pragma unroll
  for (int r = 0; r < 32; ++r) acc[r] = bj;
  for (int u = 0; u < Un; ++u){
    float wv = W1[u*Un + j];
    #pragma unroll
    for (int r = 0; r < 32; ++r) acc[r] += hl[r*Un + u]*wv;
  }
  #pragma unroll
  for (int r = 0; r < 32; ++r) hid[(size_t)(t*Bn + r)*Un + j] = f2bf(acc[r]);
}

// pg[t] via row-0 quirk
__global__ __launch_bounds__(256) void k_pg(const float* __restrict__ a_all,
    const float* __restrict__ enc_out, const float* __restrict__ h_all,
    const float* __restrict__ c0_all, const float* __restrict__ gpWs,
    const float* __restrict__ gpWc, const float* __restrict__ gpx,
    const float* __restrict__ gpWg, float* __restrict__ pg){
  __shared__ float al[Sn];
  __shared__ float cv[ENCn];
  __shared__ float red[4];
  int t = blockIdx.x, tid = threadIdx.x;
  for (int s = tid; s < Sn; s += 256) al[s] = a_all[(size_t)(t*Bn + 0)*Sn + s];
  __syncthreads();
  for (int e = tid; e < ENCn; e += 256){
    float acc = 0.f;
    for (int s = 0; s < Sn; ++s) acc += enc_out[(size_t)s*ENCn + e]*al[s];
    cv[e] = acc;
  }
  __syncthreads();
  int j = tid;
  float g = gpx[t*GPn + j];
  const float* h0r = h_all + (size_t)t*Bn*Un;       // b = 0 row
  const float* c0r = c0_all + t*Un;
  for (int u = 0; u < Un; ++u) g += h0r[u]*gpWs[u*GPn + j];
  for (int u = 0; u < Un; ++u) g += c0r[u]*gpWs[(Un+u)*GPn + j];
  for (int e = 0; e < ENCn; ++e) g += cv[e]*gpWc[e*GPn + j];
  float v = g * gpWg[j];
  int lane = tid & 63, wv2 = tid >> 6;
  #pragma unroll
  for (int m = 1; m < 64; m <<= 1) v += __shfl_xor(v, m);
  if (lane == 0) red[wv2] = v;
  __syncthreads();
  if (tid == 0) pg[t] = 1.f/(1.f+__expf(-(red[0]+red[1]+red[2]+red[3])));
}

// GEMM: A = hid [3200][256] bf16, B = W2T [32000][256] bf16. 128-row tiles.
// mode 0: Ssum[r] += sum_v exp(logit);  mode 1: probs = pg*exp/S (+OOV zeros) + amax
__global__ __launch_bounds__(512) void k_gemm(const ushort_t* __restrict__ A,
    const ushort_t* __restrict__ Bw, const float* __restrict__ b2,
    float* __restrict__ Ssum, u64* __restrict__ amax, const float* __restrict__ pg,
    float* __restrict__ probs, int mode){
  int r0 = blockIdx.x * 128;
  int n0 = blockIdx.y * 256;
  int tid = threadIdx.x;
  if (mode == 1 && n0 >= Vn){
    for (int idx = tid; idx < 128*OOVn; idx += 512){
      int i = idx/OOVn, vv = idx%OOVn;
      int r = r0+i; int tt = r>>5, bb = r&31;
      probs[(size_t)(bb*Tn+tt)*VEn + Vn + vv] = 0.f;
    }
    return;
  }
  __shared__ ushort_t Bs[64*264];          // [64 n][256 k + pad8]
  int lane = tid & 63, w = tid >> 6;       // 8 waves, 16 rows each
  bf16x8 af[8];
  {
    const ushort_t* ar = A + (size_t)(r0 + w*16 + (lane&15))*Un + (lane>>4)*8;
    #pragma unroll
    for (int kk = 0; kk < 8; ++kk) af[kk] = *(const bf16x8*)(ar + kk*32);
  }
  f32x4 acc[16];
  #pragma unroll
  for (int i = 0; i < 16; ++i) acc[i] = (f32x4){0.f,0.f,0.f,0.f};

  for (int nsub = 0; nsub < 4; ++nsub){
    __syncthreads();
    {
      const ushort_t* gb = Bw + (size_t)(n0 + nsub*64)*Un;
      #pragma unroll
      for (int i = 0; i < 4; ++i){
        int chunk = tid + i*512;
        int rr = chunk >> 5, cc = chunk & 31;
        uint4 d = *(const uint4*)(gb + rr*Un + cc*8);
        *(uint4*)(Bs + rr*264 + cc*8) = d;
      }
    }
    __syncthreads();
    #pragma unroll
    for (int kk = 0; kk < 8; ++kk){
      #pragma unroll
      for (int ntl = 0; ntl < 4; ++ntl){
        bf16x8 bf = *(const bf16x8*)(Bs + (ntl*16 + (lane&15))*264 + kk*32 + (lane>>4)*8);
        acc[nsub*4+ntl] = __builtin_amdgcn_mfma_f32_16x16x32_bf16(af[kk], bf, acc[nsub*4+ntl], 0, 0, 0);
      }
    }
  }

  int rowloc = w*16 + (lane>>4)*4;
  if (mode == 0){
    float rs[4] = {0.f,0.f,0.f,0.f};
    #pragma unroll
    for (int nt = 0; nt < 16; ++nt){
      int v = n0 + (nt>>2)*64 + (nt&3)*16 + (lane&15);
      float bb = b2[v];
      #pragma unroll
      for (int i = 0; i < 4; ++i) rs[i] += __expf(acc[nt][i] + bb);
    }
    #pragma unroll
    for (int m = 1; m < 16; m <<= 1)
      #pragma unroll
      for (int i = 0; i < 4; ++i) rs[i] += __shfl_xor(rs[i], m);
    if ((lane&15) == 0)
      #pragma unroll
      for (int i = 0; i < 4; ++i) atomicAdd(&Ssum[r0+rowloc+i], rs[i]);
  } else {
    float sc[4]; size_t obase[4];
    #pragma unroll
    for (int i = 0; i < 4; ++i){
      int r = r0+rowloc+i; int tt = r>>5, bb = r&31;
      sc[i] = pg[tt] / Ssum[r];
      obase[i] = (size_t)(bb*Tn+tt)*VEn;
    }
    u64 pm[4] = {0,0,0,0};
    #pragma unroll
    for (int nt = 0; nt < 16; ++nt){
      int v = n0 + (nt>>2)*64 + (nt&3)*16 + (lane&15);
      float bb = b2[v];
      #pragma unroll
      for (int i = 0; i < 4; ++i){
        float val = __expf(acc[nt][i] + bb) * sc[i];
        __builtin_nontemporal_store(val, &probs[obase[i] + v]);
        u64 p = ((u64)__float_as_uint(val)<<32) | (u64)(0xFFFFFFFFu - (unsigned)v);
        pm[i] = p > pm[i] ? p : pm[i];
      }
    }
    #pragma unroll
    for (int m = 1; m < 16; m <<= 1)
      #pragma unroll
      for (int i = 0; i < 4; ++i){
        u64 o = shfl_xor_u64(pm[i], m);
        pm[i] = o > pm[i] ? o : pm[i];
      }
    if ((lane&15) == 0)
      #pragma unroll
      for (int i = 0; i < 4; ++i) atomicMax(&amax[r0+rowloc+i], pm[i]);
  }
}

// scatter copy-dist via hardware atomicAdd (O(S)) + fused argmax -> seqs
__global__ __launch_bounds__(256) void k_scatter(const int* __restrict__ ext,
    const float* __restrict__ a_all, const float* __restrict__ pg,
    float* __restrict__ probs, const u64* __restrict__ amax,
    float* __restrict__ seqs){
  __shared__ int tok[Sn];
  __shared__ float val[Sn];
  __shared__ u64 wmax[4];
  int r = blockIdx.x; int t = r>>5, b = r&31;
  float c1 = 1.f - pg[t];
  int tid = threadIdx.x;
  for (int s = tid; s < Sn; s += 256){
    tok[s] = ext[b*Sn + s];
    val[s] = c1 * a_all[(size_t)r*Sn + s];
  }
  __syncthreads();
  size_t obase = (size_t)(b*Tn + t)*VEn;
  for (int s = tid; s < Sn; s += 256)
    atomicAdd(&probs[obase + tok[s]], val[s]);
  __syncthreads();   // drains vmcnt: adds acknowledged at coherence point
  u64 pm = 0;
  for (int s = tid; s < Sn; s += 256){
    int tk = tok[s];
    float nv = ld_rlx(&probs[obase + tk]);
    u64 p = ((u64)__float_as_uint(nv)<<32) | (u64)(0xFFFFFFFFu - (unsigned)tk);
    pm = p > pm ? p : pm;
  }
  #pragma unroll
  for (int m = 1; m < 64; m <<= 1){
    u64 o = shfl_xor_u64(pm, m);
    pm = o > pm ? o : pm;
  }
  int lane = tid & 63, w = tid >> 6;
  if (lane == 0) wmax[w] = pm;
  __syncthreads();
  if (tid == 0){
    u64 mm = amax[r];   // vocab-part max (complete: gemm1 precedes in stream)
    #pragma unroll
    for (int q = 0; q < 4; ++q) mm = wmax[q] > mm ? wmax[q] : mm;
    unsigned tk = 0xFFFFFFFFu - (unsigned)(mm & 0xFFFFFFFFull);
    seqs[b*Tn + t] = (float)tk;
  }
}

// ---------------- host launch ----------------

extern "C" void kernel_launch(void* const* d_in, const int* in_sizes, int n_in,
                              void* d_out, int out_size, void* d_ws, size_t ws_size,
                              hipStream_t stream){
  (void)in_sizes; (void)n_in; (void)out_size; (void)ws_size;
  const int*   gt       = (const int*)d_in[0];
  const int*   ext      = (const int*)d_in[1];
  const float* enc_out  = (const float*)d_in[2];
  const float* enc_attn = (const float*)d_in[3];
  const float* h0       = (const float*)d_in[4];
  const float* c0       = (const float*)d_in[5];
  const float* emb      = (const float*)d_in[6];
  const float* Wk       = (const float*)d_in[7];
  const float* Wr       = (const float*)d_in[8];
  const float* lb       = (const float*)d_in[9];
  const float* Wd       = (const float*)d_in[10];
  const float* bd       = (const float*)d_in[11];
  const float* Wc       = (const float*)d_in[12];
  const float* Wa       = (const float*)d_in[13];
  const float* W1       = (const float*)d_in[14];
  const float* b1       = (const float*)d_in[15];
  const float* W2       = (const float*)d_in[16];
  const float* b2       = (const float*)d_in[17];
  const float* gpWs     = (const float*)d_in[18];
  const float* gpWc     = (const float*)d_in[19];
  const float* gpWi     = (const float*)d_in[20];
  const float* gpbi     = (const float*)d_in[21];
  const float* gpWg     = (const float*)d_in[22];

  float* probs   = (float*)d_out;
  float* seqs    = probs + (size_t)Bn*Tn*VEn;
  float* covloss = seqs + Bn*Tn;

  char* wp = (char*)d_ws;
  auto carve = [&](size_t bytes)->void*{
    void* p = (void*)wp; wp += (bytes + 255) & ~(size_t)255; return p;
  };
  float*    Xall    = (float*)carve((size_t)3200*En*4);
  float*    Zx      = (float*)carve((size_t)3200*Z4n*4);
  float*    gpx     = (float*)carve((size_t)Tn*GPn*4);
  float*    h_all   = (float*)carve((size_t)Tn*Bn*Un*4);
  float*    decp    = (float*)carve((size_t)2*Bn*8*256*4);
  float*    c0_all  = (float*)carve((size_t)Tn*Un*4);
  float*    a_all   = (float*)carve((size_t)3200*Sn*4);
  ushort_t* hid_bf  = (ushort_t*)carve((size_t)3200*Un*2);
  ushort_t* W2T     = (ushort_t*)carve((size_t)Vn*Un*2);
  float*    Ssum    = (float*)carve((size_t)3200*4);
  u64*      amax    = (u64*)carve((size_t)3200*8);
  float*    pg      = (float*)carve((size_t)Tn*4);
  float*    spart2  = (float*)carve((size_t)2*Bn*96*4);
  unsigned* bars    = (unsigned*)carve((size_t)Bn*8*32*4);

  hipMemsetAsync(Ssum, 0, 3200*4, stream);
  hipMemsetAsync(amax, 0, 3200*8, stream);
  hipMemsetAsync(bars, 0, Bn*8*32*4, stream);
  hipMemsetAsync(covloss, 0, Bn*Tn*4, stream);

  k_gather<<<3200, 256, 0, stream>>>(gt, emb, Xall);
  k_zx    <<<dim3(50,16), 256, 0, stream>>>(Xall, Wk, lb, Zx);

  k_loop  <<<256, 1024, 0, stream>>>(Zx, Wr, Wd, bd, Wc, Wa, enc_attn,
                                     h0, c0, h_all, decp, c0_all,
                                     a_all, covloss, spart2, bars);

  k_w2t <<<dim3(500,4), 256, 0, stream>>>(W2, W2T);
  k_gpx <<<Tn, 256, 0, stream>>>(Xall, gpWi, gpbi, gpx);
  k_hid <<<Tn, 256, 0, stream>>>(h_all, W1, b1, hid_bf);
  k_pg  <<<Tn, 256, 0, stream>>>(a_all, enc_out, h_all, c0_all, gpWs, gpWc, gpx, gpWg, pg);
  k_gemm<<<dim3(25,125), 512, 0, stream>>>(hid_bf, W2T, b2, Ssum, amax, pg, probs, 0);
  k_gemm<<<dim3(25,126), 512, 0, stream>>>(hid_bf, W2T, b2, Ssum, amax, pg, probs, 1);
  k_scatter<<<3200, 256, 0, stream>>>(ext, a_all, pg, probs, amax, seqs);
}